// Round 15
// baseline (206.586 us; speedup 1.0000x reference)
//
#include <hip/hip_runtime.h>
#include <math.h>

typedef __attribute__((ext_vector_type(8))) short bf16x8;
typedef __attribute__((ext_vector_type(4))) float f32x4;

#define Dd 256
#define Hh 1024
#define Kk 128
#define NSTEP 1
#define MROWS 16
#define LDI 280    // in_bf row stride: 140 dw ≡ 12 (mod 32) -> ≤2-way banks (free)
#define LDH 1048   // hid row stride: 524 dw ≡ 12 (mod 32) -> ≤2-way banks
#define LDY 268    // fp32 gather stride: 268 dw ≡ 12 (mod 32)

static __device__ __forceinline__ unsigned short f2bf(float f) {
    unsigned u = __builtin_bit_cast(unsigned, f);
    unsigned r = (u + 0x7fffu + ((u >> 16) & 1u)) >> 16;   // RNE
    return (unsigned short)r;
}

static __device__ __forceinline__ float fast_tanh(float x) {
    const float e = __expf(2.0f * x);
    return 1.0f - 2.0f / (e + 1.0f);
}

// ---- merged LDS-transpose pack (UNCHANGED layouts from R13/R14 passing) ----
__global__ __launch_bounds__(256) void pack_weights(
    const float* __restrict__ W1, const float* __restrict__ W2,
    unsigned short* __restrict__ W1P, unsigned short* __restrict__ W2P)
{
    __shared__ unsigned short tile[128 * 33];   // W1 uses [32][65], W2 [128][33]
    const int tid = threadIdx.x;
    const int b = blockIdx.x;
    if (b < 128) {
        const int kst = b & 7;
        const int wpp = b >> 3;
        const int n0 = wpp * 64;
        const int k0 = kst * 32;
#pragma unroll
        for (int it = 0; it < 8; ++it) {
            const int i = it * 256 + tid;
            const int kk = i >> 6, nn = i & 63;
            tile[kk * 65 + nn] = f2bf(W1[(size_t)(k0 + kk) * Hh + n0 + nn]);
        }
        __syncthreads();
#pragma unroll
        for (int it = 0; it < 8; ++it) {
            const int i = it * 256 + tid;
            const int ct = i >> 9;
            const int lane = (i >> 3) & 63;
            const int j = i & 7;
            const int kk = (lane >> 4) * 8 + j;
            const int nn = ct * 16 + (lane & 15);
            W1P[(size_t)b * 2048 + i] = tile[kk * 65 + nn];
        }
    } else {
        const int u = b - 128;
        const int kseg = u & 7;
        const int w = u >> 3;
        const int n0 = w * 32;
        const int k0 = kseg * 128;
#pragma unroll
        for (int it = 0; it < 16; ++it) {
            const int i = it * 256 + tid;
            const int kk = i >> 5, nn = i & 31;
            tile[kk * 33 + nn] = f2bf(W2[(size_t)(k0 + kk) * Dd + n0 + nn]);
        }
        __syncthreads();
#pragma unroll
        for (int it = 0; it < 16; ++it) {
            const int i = it * 256 + tid;
            const int kst = i >> 10;
            const int ct = (i >> 9) & 1;
            const int lane = (i >> 3) & 63;
            const int j = i & 7;
            const int kk = kst * 32 + (lane >> 4) * 8 + j;
            const int nn = ct * 16 + (lane & 15);
            W2P[(size_t)u * 4096 + i] = tile[kk * 33 + nn];
        }
    }
}

// R14 kernel (passing, absmax 0.03125) with three arithmetic-preserving edits:
// (1) conflict-free LDS strides (LDI/LDH/LDY ≡ 12 mod 32 dwords),
// (2) RK4 accumulator av back in registers (VGPR=36 had headroom),
// (3) fully-unrolled K loops so the scheduler can deepen the weight-load queue.
// Per-element FP op sequences are bit-identical to R14.
__global__ __launch_bounds__(1024, 4) void ode_fused(
    const float* __restrict__ x,
    const unsigned short* __restrict__ W1P,
    const float* __restrict__ b1,
    const unsigned short* __restrict__ W2P,
    const float* __restrict__ b2,
    const int* __restrict__ indices,
    float* __restrict__ out)
{
    __shared__ __align__(16) unsigned short in_bf[MROWS * LDI];   // 8.75 KB
    __shared__ __align__(16) unsigned short hid[MROWS * LDH];     // 32.8 KB
    __shared__ float b1s[Hh];
    __shared__ float b2s[Dd];

    const int tid  = threadIdx.x;
    const int lane = tid & 63;
    const int w    = tid >> 6;      // wave 0..15
    const int quad = lane >> 4;
    const int l16  = lane & 15;
    const int row0 = blockIdx.x * MROWS;

    for (int i = tid; i < Hh; i += 1024) b1s[i] = b1[i];
    for (int i = tid; i < Dd; i += 1024) b2s[i] = b2[i];

    // state: yv/av[r] -> batch row = l16, col = w*16 + quad*4 + r
    float yv[4], av[4];
    const int scol = w * 16 + quad * 4;
    {
        const float4 v = *(const float4*)&x[(size_t)(row0 + l16) * Dd + scol];
        yv[0] = v.x; yv[1] = v.y; yv[2] = v.z; yv[3] = v.w;
        const unsigned u0 = (unsigned)f2bf(v.x) | ((unsigned)f2bf(v.y) << 16);
        const unsigned u1 = (unsigned)f2bf(v.z) | ((unsigned)f2bf(v.w) << 16);
        *(uint2*)&in_bf[l16 * LDI + scol] = make_uint2(u0, u1);
    }
    __syncthreads();

    const float h  = 1.0f / NSTEP;
    const float h6 = h / 6.0f, h3 = h / 3.0f, h2 = h * 0.5f;

    const unsigned short* w1w = W1P + (size_t)w * 16384 + (size_t)lane * 8;
    const unsigned short* w2w = W2P + (size_t)(w >> 1) * 32768
                                    + (size_t)(w & 1) * 512 + (size_t)lane * 8;

#pragma unroll 1
    for (int s = 0; s < NSTEP; ++s) {
#pragma unroll 1
        for (int e = 0; e < 4; ++e) {
            // ---- GEMM1: hid cols [w*64,+64) = tanh(in_bf @ W1 + b1)
            f32x4 acc[4] = {};
#pragma unroll
            for (int kst = 0; kst < 8; ++kst) {
                const bf16x8 bf = *(const bf16x8*)&in_bf[l16 * LDI + kst * 32 + quad * 8];
                bf16x8 aw[4];
#pragma unroll
                for (int ct = 0; ct < 4; ++ct)
                    aw[ct] = *(const bf16x8*)(w1w + (size_t)(kst * 4 + ct) * 512);
#pragma unroll
                for (int ct = 0; ct < 4; ++ct)
                    acc[ct] = __builtin_amdgcn_mfma_f32_16x16x32_bf16(
                        aw[ct], bf, acc[ct], 0, 0, 0);
            }
#pragma unroll
            for (int ct = 0; ct < 4; ++ct) {
                const int col = w * 64 + ct * 16 + quad * 4;
                const float4 bb = *(const float4*)&b1s[col];
                const unsigned short h0 = f2bf(fast_tanh(acc[ct][0] + bb.x));
                const unsigned short h1 = f2bf(fast_tanh(acc[ct][1] + bb.y));
                const unsigned short h2b = f2bf(fast_tanh(acc[ct][2] + bb.z));
                const unsigned short h3b = f2bf(fast_tanh(acc[ct][3] + bb.w));
                const unsigned u0 = (unsigned)h0 | ((unsigned)h1 << 16);
                const unsigned u1 = (unsigned)h2b | ((unsigned)h3b << 16);
                *(uint2*)&hid[l16 * LDH + col] = make_uint2(u0, u1);
            }
            __syncthreads();

            // ---- GEMM2: F for state cols [w*16,+16) = hid @ W2 + b2
            f32x4 acc2 = {};
#pragma unroll
            for (int kseg = 0; kseg < 8; ++kseg) {
#pragma unroll
                for (int kst = 0; kst < 4; ++kst) {
                    const bf16x8 bh = *(const bf16x8*)&hid[l16 * LDH + kseg * 128 + kst * 32 + quad * 8];
                    const bf16x8 aw = *(const bf16x8*)(w2w + (size_t)(kseg * 4 + kst) * 1024);
                    acc2 = __builtin_amdgcn_mfma_f32_16x16x32_bf16(aw, bh, acc2, 0, 0, 0);
                }
            }
            // ---- RK4 stage update (av in registers)
            {
                const float4 bb = *(const float4*)&b2s[scol];
                float tmp[4];
#pragma unroll
                for (int r = 0; r < 4; ++r) {
                    const float F = acc2[r] + ((const float*)&bb)[r];
                    if (e == 0)      { av[r] = yv[r] + h6 * F; tmp[r] = yv[r] + h2 * F; }
                    else if (e == 1) { av[r] += h3 * F;        tmp[r] = yv[r] + h2 * F; }
                    else if (e == 2) { av[r] += h3 * F;        tmp[r] = yv[r] + h  * F; }
                    else             { yv[r] = av[r] + h6 * F; tmp[r] = yv[r]; }
                }
                const unsigned u0 = (unsigned)f2bf(tmp[0]) | ((unsigned)f2bf(tmp[1]) << 16);
                const unsigned u1 = (unsigned)f2bf(tmp[2]) | ((unsigned)f2bf(tmp[3]) << 16);
                *(uint2*)&in_bf[l16 * LDI + scol] = make_uint2(u0, u1);
            }
            __syncthreads();
        }
    }

    // final state -> LDS (reuse hid as fp32) -> gather
    float* yf = (float*)hid;
    {
        float4 v;
        v.x = yv[0]; v.y = yv[1]; v.z = yv[2]; v.w = yv[3];
        *(float4*)&yf[l16 * LDY + scol] = v;
    }
    __syncthreads();

    for (int i = tid; i < MROWS * Kk; i += 1024) {
        const int row = i >> 7;
        const int kc  = i & (Kk - 1);
        const int gi  = (row0 + row) * Kk + kc;
        out[gi] = yf[row * LDY + indices[gi]];
    }
}

extern "C" void kernel_launch(void* const* d_in, const int* in_sizes, int n_in,
                              void* d_out, int out_size, void* d_ws, size_t ws_size,
                              hipStream_t stream)
{
    const float* x  = (const float*)d_in[0];
    const float* W1 = (const float*)d_in[1];
    const float* b1 = (const float*)d_in[2];
    const float* W2 = (const float*)d_in[3];
    const float* b2 = (const float*)d_in[4];
    const int* indices = (const int*)d_in[5];
    float* out = (float*)d_out;

    const int H = in_sizes[2];        // 1024
    const int D = in_sizes[4];        // 256
    const int B = in_sizes[0] / D;    // 4096

    unsigned short* W1P = (unsigned short*)d_ws;                 // 512 KB
    unsigned short* W2P = W1P + (size_t)H * D;                   // 512 KB

    pack_weights<<<192, 256, 0, stream>>>(W1, W2, W1P, W2P);

    ode_fused<<<B / MROWS, 1024, 0, stream>>>(x, W1P, b1, W2P, b2, indices, out);
}

// Round 16
// 115.608 us; speedup vs baseline: 1.7869x; 1.7869x over previous
//
#include <hip/hip_runtime.h>
#include <math.h>

typedef __attribute__((ext_vector_type(8))) short bf16x8;
typedef __attribute__((ext_vector_type(4))) float f32x4;

#define Dd 256
#define Hh 1024
#define Kk 128
#define NSTEP 1
#define MROWS 16
#define LDI 280    // in_bf row stride: 140 dw ≡ 12 (mod 32) -> ≤2-way banks (free)
#define LDH 1048   // hid row stride: 524 dw ≡ 12 (mod 32) -> ≤2-way banks
#define LDY 268    // fp32 gather stride: 268 dw ≡ 12 (mod 32)

static __device__ __forceinline__ unsigned short f2bf(float f) {
    unsigned u = __builtin_bit_cast(unsigned, f);
    unsigned r = (u + 0x7fffu + ((u >> 16) & 1u)) >> 16;   // RNE
    return (unsigned short)r;
}

static __device__ __forceinline__ float fast_tanh(float x) {
    const float e = __expf(2.0f * x);
    return 1.0f - 2.0f / (e + 1.0f);
}

// ---- merged LDS-transpose pack (UNCHANGED layouts from R13/R14 passing) ----
__global__ __launch_bounds__(256) void pack_weights(
    const float* __restrict__ W1, const float* __restrict__ W2,
    unsigned short* __restrict__ W1P, unsigned short* __restrict__ W2P)
{
    __shared__ unsigned short tile[128 * 33];   // W1 uses [32][65], W2 [128][33]
    const int tid = threadIdx.x;
    const int b = blockIdx.x;
    if (b < 128) {
        const int kst = b & 7;
        const int wpp = b >> 3;
        const int n0 = wpp * 64;
        const int k0 = kst * 32;
#pragma unroll
        for (int it = 0; it < 8; ++it) {
            const int i = it * 256 + tid;
            const int kk = i >> 6, nn = i & 63;
            tile[kk * 65 + nn] = f2bf(W1[(size_t)(k0 + kk) * Hh + n0 + nn]);
        }
        __syncthreads();
#pragma unroll
        for (int it = 0; it < 8; ++it) {
            const int i = it * 256 + tid;
            const int ct = i >> 9;
            const int lane = (i >> 3) & 63;
            const int j = i & 7;
            const int kk = (lane >> 4) * 8 + j;
            const int nn = ct * 16 + (lane & 15);
            W1P[(size_t)b * 2048 + i] = tile[kk * 65 + nn];
        }
    } else {
        const int u = b - 128;
        const int kseg = u & 7;
        const int w = u >> 3;
        const int n0 = w * 32;
        const int k0 = kseg * 128;
#pragma unroll
        for (int it = 0; it < 16; ++it) {
            const int i = it * 256 + tid;
            const int kk = i >> 5, nn = i & 31;
            tile[kk * 33 + nn] = f2bf(W2[(size_t)(k0 + kk) * Dd + n0 + nn]);
        }
        __syncthreads();
#pragma unroll
        for (int it = 0; it < 16; ++it) {
            const int i = it * 256 + tid;
            const int kst = i >> 10;
            const int ct = (i >> 9) & 1;
            const int lane = (i >> 3) & 63;
            const int j = i & 7;
            const int kk = kst * 32 + (lane >> 4) * 8 + j;
            const int nn = ct * 16 + (lane & 15);
            W2P[(size_t)u * 4096 + i] = tile[kk * 33 + nn];
        }
    }
}

// R14 kernel (passing, 58 µs, VGPR=36, no spill) with ONLY two
// arithmetic-preserving edits this round (R15 lesson: full unroll extends
// load lifetimes -> 64-reg tier spill; keep R14's unroll 2):
// (1) conflict-free LDS strides (LDI/LDH/LDY ≡ 12 mod 32 dwords),
// (2) RK4 accumulator av in registers (+8 VGPR from base 36).
__global__ __launch_bounds__(1024, 4) void ode_fused(
    const float* __restrict__ x,
    const unsigned short* __restrict__ W1P,
    const float* __restrict__ b1,
    const unsigned short* __restrict__ W2P,
    const float* __restrict__ b2,
    const int* __restrict__ indices,
    float* __restrict__ out)
{
    __shared__ __align__(16) unsigned short in_bf[MROWS * LDI];   // 8.75 KB
    __shared__ __align__(16) unsigned short hid[MROWS * LDH];     // 32.8 KB
    __shared__ float b1s[Hh];
    __shared__ float b2s[Dd];

    const int tid  = threadIdx.x;
    const int lane = tid & 63;
    const int w    = tid >> 6;      // wave 0..15
    const int quad = lane >> 4;
    const int l16  = lane & 15;
    const int row0 = blockIdx.x * MROWS;

    for (int i = tid; i < Hh; i += 1024) b1s[i] = b1[i];
    for (int i = tid; i < Dd; i += 1024) b2s[i] = b2[i];

    // state: yv/av[r] -> batch row = l16, col = w*16 + quad*4 + r
    float yv[4], av[4];
    const int scol = w * 16 + quad * 4;
    {
        const float4 v = *(const float4*)&x[(size_t)(row0 + l16) * Dd + scol];
        yv[0] = v.x; yv[1] = v.y; yv[2] = v.z; yv[3] = v.w;
        const unsigned u0 = (unsigned)f2bf(v.x) | ((unsigned)f2bf(v.y) << 16);
        const unsigned u1 = (unsigned)f2bf(v.z) | ((unsigned)f2bf(v.w) << 16);
        *(uint2*)&in_bf[l16 * LDI + scol] = make_uint2(u0, u1);
    }
    __syncthreads();

    const float h  = 1.0f / NSTEP;
    const float h6 = h / 6.0f, h3 = h / 3.0f, h2 = h * 0.5f;

    const unsigned short* w1w = W1P + (size_t)w * 16384 + (size_t)lane * 8;
    const unsigned short* w2w = W2P + (size_t)(w >> 1) * 32768
                                    + (size_t)(w & 1) * 512 + (size_t)lane * 8;

#pragma unroll 1
    for (int s = 0; s < NSTEP; ++s) {
#pragma unroll 1
        for (int e = 0; e < 4; ++e) {
            // ---- GEMM1: hid cols [w*64,+64) = tanh(in_bf @ W1 + b1)
            f32x4 acc[4] = {};
#pragma unroll 2
            for (int kst = 0; kst < 8; ++kst) {
                const bf16x8 bf = *(const bf16x8*)&in_bf[l16 * LDI + kst * 32 + quad * 8];
                bf16x8 aw[4];
#pragma unroll
                for (int ct = 0; ct < 4; ++ct)
                    aw[ct] = *(const bf16x8*)(w1w + (size_t)(kst * 4 + ct) * 512);
#pragma unroll
                for (int ct = 0; ct < 4; ++ct)
                    acc[ct] = __builtin_amdgcn_mfma_f32_16x16x32_bf16(
                        aw[ct], bf, acc[ct], 0, 0, 0);
            }
#pragma unroll
            for (int ct = 0; ct < 4; ++ct) {
                const int col = w * 64 + ct * 16 + quad * 4;
                const float4 bb = *(const float4*)&b1s[col];
                const unsigned short h0 = f2bf(fast_tanh(acc[ct][0] + bb.x));
                const unsigned short h1 = f2bf(fast_tanh(acc[ct][1] + bb.y));
                const unsigned short h2b = f2bf(fast_tanh(acc[ct][2] + bb.z));
                const unsigned short h3b = f2bf(fast_tanh(acc[ct][3] + bb.w));
                const unsigned u0 = (unsigned)h0 | ((unsigned)h1 << 16);
                const unsigned u1 = (unsigned)h2b | ((unsigned)h3b << 16);
                *(uint2*)&hid[l16 * LDH + col] = make_uint2(u0, u1);
            }
            __syncthreads();

            // ---- GEMM2: F for state cols [w*16,+16) = hid @ W2 + b2
            f32x4 acc2 = {};
#pragma unroll 2
            for (int kseg = 0; kseg < 8; ++kseg) {
#pragma unroll
                for (int kst = 0; kst < 4; ++kst) {
                    const bf16x8 bh = *(const bf16x8*)&hid[l16 * LDH + kseg * 128 + kst * 32 + quad * 8];
                    const bf16x8 aw = *(const bf16x8*)(w2w + (size_t)(kseg * 4 + kst) * 1024);
                    acc2 = __builtin_amdgcn_mfma_f32_16x16x32_bf16(aw, bh, acc2, 0, 0, 0);
                }
            }
            // ---- RK4 stage update (av in registers)
            {
                const float4 bb = *(const float4*)&b2s[scol];
                float tmp[4];
#pragma unroll
                for (int r = 0; r < 4; ++r) {
                    const float F = acc2[r] + ((const float*)&bb)[r];
                    if (e == 0)      { av[r] = yv[r] + h6 * F; tmp[r] = yv[r] + h2 * F; }
                    else if (e == 1) { av[r] += h3 * F;        tmp[r] = yv[r] + h2 * F; }
                    else if (e == 2) { av[r] += h3 * F;        tmp[r] = yv[r] + h  * F; }
                    else             { yv[r] = av[r] + h6 * F; tmp[r] = yv[r]; }
                }
                const unsigned u0 = (unsigned)f2bf(tmp[0]) | ((unsigned)f2bf(tmp[1]) << 16);
                const unsigned u1 = (unsigned)f2bf(tmp[2]) | ((unsigned)f2bf(tmp[3]) << 16);
                *(uint2*)&in_bf[l16 * LDI + scol] = make_uint2(u0, u1);
            }
            __syncthreads();
        }
    }

    // final state -> LDS (reuse hid as fp32) -> gather
    float* yf = (float*)hid;
    {
        float4 v;
        v.x = yv[0]; v.y = yv[1]; v.z = yv[2]; v.w = yv[3];
        *(float4*)&yf[l16 * LDY + scol] = v;
    }
    __syncthreads();

    for (int i = tid; i < MROWS * Kk; i += 1024) {
        const int row = i >> 7;
        const int kc  = i & (Kk - 1);
        const int gi  = (row0 + row) * Kk + kc;
        out[gi] = yf[row * LDY + indices[gi]];
    }
}

extern "C" void kernel_launch(void* const* d_in, const int* in_sizes, int n_in,
                              void* d_out, int out_size, void* d_ws, size_t ws_size,
                              hipStream_t stream)
{
    const float* x  = (const float*)d_in[0];
    const float* W1 = (const float*)d_in[1];
    const float* b1 = (const float*)d_in[2];
    const float* W2 = (const float*)d_in[3];
    const float* b2 = (const float*)d_in[4];
    const int* indices = (const int*)d_in[5];
    float* out = (float*)d_out;

    const int H = in_sizes[2];        // 1024
    const int D = in_sizes[4];        // 256
    const int B = in_sizes[0] / D;    // 4096

    unsigned short* W1P = (unsigned short*)d_ws;                 // 512 KB
    unsigned short* W2P = W1P + (size_t)H * D;                   // 512 KB

    pack_weights<<<192, 256, 0, stream>>>(W1, W2, W1P, W2P);

    ode_fused<<<B / MROWS, 1024, 0, stream>>>(x, W1P, b1, W2P, b2, indices, out);
}